// Round 1
// baseline (131.692 us; speedup 1.0000x reference)
//
#include <hip/hip_runtime.h>
#include <hip/hip_bf16.h>

// Problem shapes
#define B_SZ 64
#define T_PTS 300
#define N_SEG 299
#define VM 34            // 17*2
#define NPATH (B_SZ*VM)  // 2176
#define SIGC 120         // 3+9+27+81
#define FAN1 4080        // 34*120
#define H1 512
#define NOUT 155
#define GSZ 64           // lanes per path in sig (full wave)
#define CHUNK 5          // segments per lane (64*5=320 >= 299)
#define TT 75            // transpose t-tile (300/4)
#define KSPL 48          // gemm1 K-splits
#define KW 85            // k per wave (48*85 = 4080)

// ---------------------------------------------------------------------------
// Absorb one linear segment with increment (d0,d1,d2) into state a1..a4.
// All array indices compile-time constant -> stays in VGPRs.
// ---------------------------------------------------------------------------
__device__ __forceinline__ void sig_append(float a1[3], float a2[9], float a3[27], float a4[81],
                                           float d0, float d1, float d2) {
  float B1[3] = {d0, d1, d2};
  float Hh[3] = {0.5f * d0, 0.5f * d1, 0.5f * d2};
  float Tt[3] = {(1.0f / 3.0f) * d0, (1.0f / 3.0f) * d1, (1.0f / 3.0f) * d2};
  float Qq[3] = {0.25f * d0, 0.25f * d1, 0.25f * d2};
  float B2[9], B3[27];
#pragma unroll
  for (int i = 0; i < 3; i++)
#pragma unroll
    for (int j = 0; j < 3; j++) B2[i * 3 + j] = B1[i] * Hh[j];
#pragma unroll
  for (int e = 0; e < 27; e++) B3[e] = B2[e / 3] * Tt[e % 3];

#pragma unroll
  for (int e = 0; e < 81; e++) {
    float v = a4[e];
    v = fmaf(B3[e / 3], Qq[e % 3], v);       // + g4[e]
    v = fmaf(a3[e / 3], B1[e % 3], v);       // + a3 (x) g1
    v = fmaf(a2[e / 9], B2[e % 9], v);       // + a2 (x) g2
    v = fmaf(a1[e / 27], B3[e % 27], v);     // + a1 (x) g3
    a4[e] = v;
  }
#pragma unroll
  for (int e = 0; e < 27; e++) {
    float v = a3[e] + B3[e];
    v = fmaf(a2[e / 3], B1[e % 3], v);
    v = fmaf(a1[e / 9], B2[e % 9], v);
    a3[e] = v;
  }
#pragma unroll
  for (int e = 0; e < 9; e++) a2[e] = fmaf(a1[e / 3], B1[e % 3], a2[e] + B2[e]);
  a1[0] += d0; a1[1] += d1; a1[2] += d2;
}

// ---------------------------------------------------------------------------
// Kernel 0: transpose (B,C,T,V,M) -> (P=B*VM, T, C) contiguous paths; fused
// ht = broadcast(b1) init (gemm1 accumulates atomically on top).
// ---------------------------------------------------------------------------
__global__ __launch_bounds__(256) void transpose_kernel(const float* __restrict__ inp,
                                                        float* __restrict__ tp,
                                                        const float* __restrict__ b1,
                                                        float* __restrict__ ht) {
  const int b = blockIdx.x;       // 0..63
  const int tile = blockIdx.y;    // 0..3
  const int t0 = tile * TT;
  const int tid = threadIdx.x;
  __shared__ float lds[3 * TT * VM];  // 7650 floats = 30.6 KB

  const float* src = inp + (size_t)b * 3 * T_PTS * VM;
  for (int idx = tid; idx < 3 * TT * VM; idx += 256) {
    const int c = idx / (TT * VM);
    const int rem = idx - c * (TT * VM);
    lds[idx] = src[(c * T_PTS + t0) * VM + rem];
  }
  __syncthreads();

  for (int idx = tid; idx < VM * TT * 3; idx += 256) {
    const int vm = idx / (TT * 3);
    const int i = idx - vm * (TT * 3);
    const int tt = i / 3;
    const int c = i - tt * 3;
    tp[((size_t)(b * VM + vm) * T_PTS + t0 + tt) * 3 + c] = lds[(c * TT + tt) * VM + vm];
  }

  if (tile == 0) {
    // ht[j][bb] = b1[j] for j in [8b, 8b+8)
    for (int idx = tid; idx < 8 * 64; idx += 256)
      ht[(size_t)(8 * b) * 64 + idx] = b1[8 * b + (idx >> 6)];
  }
}

// ---------------------------------------------------------------------------
// Kernel 1: signatures. One PATH per WAVE now (was 4 paths/wave, 16 lanes
// each): 64 lanes x 5 segments each, then a 6-round full-wave Kogge-Stone
// suffix Chen combine. This quadruples wave count (544 -> 2176 waves =
// ~2.1 waves/SIMD across the chip) AND halves per-lane sequential work
// (19 sig_appends -> 5 + 2 extra combine rounds). The old version left
// half the SIMDs idle (OccupancyPercent 5.4, VALUBusy 11.5).
// Output written TRANSPOSED: St[k][b], k = vm*120 + c.
// ---------------------------------------------------------------------------
__global__ __launch_bounds__(256)
__attribute__((amdgpu_waves_per_eu(1)))
void sig_kernel(const float* __restrict__ tp, float* __restrict__ St) {
  const int lane = threadIdx.x & 63;
  const int wv = threadIdx.x >> 6;      // wave within block: 0..3
  const int p = blockIdx.x * 4 + wv;    // 544 blocks * 4 waves = 2176 paths
  const int sub = lane;                 // lane within 64-lane group
  const int t0 = sub * CHUNK;

  const float* bp = tp + (size_t)p * (T_PTS * 3) + t0 * 3;

  float a1[3], a2[9], a3[27], a4[81];
#pragma unroll
  for (int i = 0; i < 3; i++) a1[i] = 0.f;
#pragma unroll
  for (int i = 0; i < 9; i++) a2[i] = 0.f;
#pragma unroll
  for (int i = 0; i < 27; i++) a3[i] = 0.f;
#pragma unroll
  for (int i = 0; i < 81; i++) a4[i] = 0.f;

  float x0 = bp[0], x1 = bp[1], x2 = bp[2];
#pragma unroll
  for (int s = 0; s < CHUNK; s++) {
    // Over-reads (up to point 320) stay inside ws (St follows tp) and are
    // masked off below.
    const float y0 = bp[3 * s + 3];
    const float y1 = bp[3 * s + 4];
    const float y2 = bp[3 * s + 5];
    const bool valid = (t0 + s) < N_SEG;
    const float d0 = valid ? (y0 - x0) : 0.0f;
    const float d1 = valid ? (y1 - x1) : 0.0f;
    const float d2 = valid ? (y2 - x2) : 0.0f;
    sig_append(a1, a2, a3, a4, d0, d1, d2);
    x0 = y0; x1 = y1; x2 = y2;
  }

  // Kogge-Stone suffix Chen product across the full 64-lane wave.
#pragma unroll
  for (int off = 1; off < GSZ; off <<= 1) {
    const float m = (sub + off < GSZ) ? 1.0f : 0.0f;  // zero state = identity
    float B1[3], B2[9], B3[27];
#pragma unroll
    for (int i = 0; i < 3; i++) B1[i] = m * __shfl_down(a1[i], off);
#pragma unroll
    for (int i = 0; i < 9; i++) B2[i] = m * __shfl_down(a2[i], off);
#pragma unroll
    for (int i = 0; i < 27; i++) B3[i] = m * __shfl_down(a3[i], off);

#pragma unroll
    for (int e = 0; e < 81; e++) {
      const float b4 = m * __shfl_down(a4[e], off);  // reads pre-update a4[e]
      float v = a4[e] + b4;
      v = fmaf(a3[e / 3], B1[e % 3], v);
      v = fmaf(a2[e / 9], B2[e % 9], v);
      v = fmaf(a1[e / 27], B3[e % 27], v);
      a4[e] = v;
    }
#pragma unroll
    for (int e = 0; e < 27; e++) {
      float v = a3[e] + B3[e];
      v = fmaf(a2[e / 3], B1[e % 3], v);
      v = fmaf(a1[e / 9], B2[e % 9], v);
      a3[e] = v;
    }
#pragma unroll
    for (int e = 0; e < 9; e++) a2[e] = fmaf(a1[e / 3], B1[e % 3], a2[e] + B2[e]);
#pragma unroll
    for (int i = 0; i < 3; i++) a1[i] += B1[i];
  }

  if (sub == 0) {
    const int b = p / VM;
    const int vm = p - b * VM;
    float* dst = St + (size_t)(vm * SIGC) * 64 + b;  // St[(vm*120+i)*64 + b]
#pragma unroll
    for (int i = 0; i < 3; i++) dst[(size_t)i * 64] = a1[i];
#pragma unroll
    for (int i = 0; i < 9; i++) dst[(size_t)(3 + i) * 64] = a2[i];
#pragma unroll
    for (int i = 0; i < 27; i++) dst[(size_t)(12 + i) * 64] = a3[i];
#pragma unroll
    for (int i = 0; i < 81; i++) dst[(size_t)(39 + i) * 64] = a4[i];
  }
}

// ---------------------------------------------------------------------------
// Kernel 2: ht[j][b] += sum_k St[k][b] * W1[j][k].  lane = b (M=64=wave).
// 6144 waves: 48 K-splits (85 k each) x 128 j-groups (4 j each) -> ~4
// waves/SIMD for latency hiding. St chunk fully unrolled into 85 VGPRs
// (static indices, no scratch); W1 rows are wave-uniform streams (scalar
// loads, one SGPR operand per FMA). Coalesced atomicAdd epilogue onto the
// b1-initialized ht (48 adds/element, order-independent).
// ---------------------------------------------------------------------------
__global__ __launch_bounds__(256) void gemm1_kernel(const float* __restrict__ St,
                                                    const float* __restrict__ W1,
                                                    float* __restrict__ ht) {
  const int lane = threadIdx.x & 63;
  int wave_id = (blockIdx.x * 256 + threadIdx.x) >> 6;        // 0..6143
  wave_id = __builtin_amdgcn_readfirstlane(wave_id);          // force SGPR
  const int ks = wave_id / 128;   // 0..47  (k-range of 85)
  const int jg = wave_id & 127;   // 0..127 (4 j's each)
  const int k0 = ks * KW;

  const float* stp = St + (size_t)k0 * 64 + lane;
  const float* w0 = W1 + (size_t)(jg * 4 + 0) * FAN1 + k0;    // uniform -> s_load
  const float* w1 = W1 + (size_t)(jg * 4 + 1) * FAN1 + k0;
  const float* w2 = W1 + (size_t)(jg * 4 + 2) * FAN1 + k0;
  const float* w3 = W1 + (size_t)(jg * 4 + 3) * FAN1 + k0;

  float sv[KW];
#pragma unroll
  for (int i = 0; i < KW; i++) sv[i] = stp[(size_t)i * 64];

  float acc0 = 0.f, acc1 = 0.f, acc2 = 0.f, acc3 = 0.f;
#pragma unroll
  for (int i = 0; i < KW; i++) {
    acc0 = fmaf(sv[i], w0[i], acc0);
    acc1 = fmaf(sv[i], w1[i], acc1);
    acc2 = fmaf(sv[i], w2[i], acc2);
    acc3 = fmaf(sv[i], w3[i], acc3);
  }

  float* hp = ht + (size_t)(jg * 4) * 64 + lane;
  atomicAdd(hp + 0 * 64, acc0);
  atomicAdd(hp + 1 * 64, acc1);
  atomicAdd(hp + 2 * 64, acc2);
  atomicAdd(hp + 3 * 64, acc3);
}

// ---------------------------------------------------------------------------
// Kernel 3: out[b][j] = sum_k2 ht[k2][b] * W2[j][k2] + b2[j].  lane = b.
// Block = one j; 4 waves split k2 (128 each); LDS partial reduce; single
// non-atomic store (no out-init needed).
// ---------------------------------------------------------------------------
__global__ __launch_bounds__(256) void gemm2_kernel(const float* __restrict__ ht,
                                                    const float* __restrict__ W2,
                                                    const float* __restrict__ b2,
                                                    float* __restrict__ out) {
  const int j = blockIdx.x;              // 0..154
  const int lane = threadIdx.x & 63;
  int w = threadIdx.x >> 6;              // 0..3
  w = __builtin_amdgcn_readfirstlane(w);
  __shared__ float red[4][64];

  const float* htp = ht + (size_t)(w * 128) * 64 + lane;
  const float* w2r = W2 + (size_t)j * H1 + w * 128;  // uniform -> s_load
  float acc = 0.f;
#pragma unroll 8
  for (int k = 0; k < 128; k++) acc = fmaf(w2r[k], htp[(size_t)k * 64], acc);

  red[w][lane] = acc;
  __syncthreads();
  if (threadIdx.x < 64) {
    const float tot = red[0][lane] + red[1][lane] + red[2][lane] + red[3][lane];
    out[(size_t)lane * NOUT + j] = tot + b2[j];
  }
}

// ---------------------------------------------------------------------------
extern "C" void kernel_launch(void* const* d_in, const int* in_sizes, int n_in,
                              void* d_out, int out_size, void* d_ws, size_t ws_size,
                              hipStream_t stream) {
  const float* inp = (const float*)d_in[0];  // (64,3,300,17,2)
  const float* W1  = (const float*)d_in[1];  // (512,4080)
  const float* b1  = (const float*)d_in[2];  // (512,)
  const float* W2  = (const float*)d_in[3];  // (155,512)
  const float* b2  = (const float*)d_in[4];  // (155,)
  float* out = (float*)d_out;                // (64,155)

  // ws layout (floats): tp | St | ht   (~9.0 MB total)
  float* tpbuf = (float*)d_ws;                       // 2176*900
  float* St    = tpbuf + (size_t)NPATH * T_PTS * 3;  // 4080*64
  float* ht    = St + (size_t)FAN1 * 64;             // 512*64

  transpose_kernel<<<dim3(B_SZ, 4), 256, 0, stream>>>(inp, tpbuf, b1, ht);
  sig_kernel<<<NPATH / 4, 256, 0, stream>>>(tpbuf, St);
  gemm1_kernel<<<KSPL * 128 / 4, 256, 0, stream>>>(St, W1, ht);
  gemm2_kernel<<<NOUT, 256, 0, stream>>>(ht, W2, b2, out);
}

// Round 2
// 118.996 us; speedup vs baseline: 1.1067x; 1.1067x over previous
//
#include <hip/hip_runtime.h>
#include <hip/hip_bf16.h>

// Problem shapes
#define B_SZ 64
#define T_PTS 300
#define N_SEG 299
#define VM 34            // 17*2
#define NPATH (B_SZ*VM)  // 2176
#define SIGC 120         // 3+9+27+81
#define FAN1 4080        // 34*120
#define H1 512
#define NOUT 155
#define CHUNK 5          // segments per lane (64*5=320 >= 299)
#define TT 75            // transpose t-tile (300/4)
#define KSPL 48          // gemm1 K-splits
#define KW 85            // k per wave (48*85 = 4080)

// ---------------------------------------------------------------------------
// Absorb one linear segment with increment (d0,d1,d2) into state a1..a4.
// All array indices compile-time constant -> stays in VGPRs.
// ---------------------------------------------------------------------------
__device__ __forceinline__ void sig_append(float a1[3], float a2[9], float a3[27], float a4[81],
                                           float d0, float d1, float d2) {
  float B1[3] = {d0, d1, d2};
  float Hh[3] = {0.5f * d0, 0.5f * d1, 0.5f * d2};
  float Tt[3] = {(1.0f / 3.0f) * d0, (1.0f / 3.0f) * d1, (1.0f / 3.0f) * d2};
  float Qq[3] = {0.25f * d0, 0.25f * d1, 0.25f * d2};
  float B2[9], B3[27];
#pragma unroll
  for (int i = 0; i < 3; i++)
#pragma unroll
    for (int j = 0; j < 3; j++) B2[i * 3 + j] = B1[i] * Hh[j];
#pragma unroll
  for (int e = 0; e < 27; e++) B3[e] = B2[e / 3] * Tt[e % 3];

#pragma unroll
  for (int e = 0; e < 81; e++) {
    float v = a4[e];
    v = fmaf(B3[e / 3], Qq[e % 3], v);       // + g4[e]
    v = fmaf(a3[e / 3], B1[e % 3], v);       // + a3 (x) g1
    v = fmaf(a2[e / 9], B2[e % 9], v);       // + a2 (x) g2
    v = fmaf(a1[e / 27], B3[e % 27], v);     // + a1 (x) g3
    a4[e] = v;
  }
#pragma unroll
  for (int e = 0; e < 27; e++) {
    float v = a3[e] + B3[e];
    v = fmaf(a2[e / 3], B1[e % 3], v);
    v = fmaf(a1[e / 9], B2[e % 9], v);
    a3[e] = v;
  }
#pragma unroll
  for (int e = 0; e < 9; e++) a2[e] = fmaf(a1[e / 3], B1[e % 3], a2[e] + B2[e]);
  a1[0] += d0; a1[1] += d1; a1[2] += d2;
}

// ---------------------------------------------------------------------------
// Cross-lane fetch for the Chen combine.
//   OFF < 16 : DPP row_shl:OFF  -> lane i reads lane i+OFF within its 16-lane
//              row; out-of-row lanes get 0 (= Chen identity). VALU pipe, no
//              DS traffic, no mask-multiply needed.
//              (rocPRIM prefix-scan uses row_shr:N = read lane i-N, so the
//               suffix direction is row_shl:N = read lane i+N.)
//   OFF >= 16: __shfl_xor butterfly. Only lane 0's chain is consumed; its
//              partners (lane 16 pre-round, lane 32 post-round-16) are always
//              valid suffix products, so no mask is needed.
// ---------------------------------------------------------------------------
template <int OFF>
__device__ __forceinline__ float lane_down(float x) {
  if constexpr (OFF < 16) {
    return __int_as_float(__builtin_amdgcn_update_dpp(
        0, __float_as_int(x), 0x100 + OFF /*row_shl:OFF*/, 0xF, 0xF, true));
  } else {
    return __shfl_xor(x, OFF);
  }
}

// One Chen-combine round: state <- state (x) fetched-state.
template <int OFF>
__device__ __forceinline__ void chen_round(float a1[3], float a2[9], float a3[27], float a4[81]) {
  float B1[3], B2[9], B3[27];
#pragma unroll
  for (int i = 0; i < 3; i++) B1[i] = lane_down<OFF>(a1[i]);
#pragma unroll
  for (int i = 0; i < 9; i++) B2[i] = lane_down<OFF>(a2[i]);
#pragma unroll
  for (int i = 0; i < 27; i++) B3[i] = lane_down<OFF>(a3[i]);

#pragma unroll
  for (int e = 0; e < 81; e++) {
    const float b4 = lane_down<OFF>(a4[e]);  // reads pre-update a4[e]
    float v = a4[e] + b4;
    v = fmaf(a3[e / 3], B1[e % 3], v);
    v = fmaf(a2[e / 9], B2[e % 9], v);
    v = fmaf(a1[e / 27], B3[e % 27], v);
    a4[e] = v;
  }
#pragma unroll
  for (int e = 0; e < 27; e++) {
    float v = a3[e] + B3[e];
    v = fmaf(a2[e / 3], B1[e % 3], v);
    v = fmaf(a1[e / 9], B2[e % 9], v);
    a3[e] = v;
  }
#pragma unroll
  for (int e = 0; e < 9; e++) a2[e] = fmaf(a1[e / 3], B1[e % 3], a2[e] + B2[e]);
#pragma unroll
  for (int i = 0; i < 3; i++) a1[i] += B1[i];
}

// ---------------------------------------------------------------------------
// Kernel 0: transpose (B,C,T,V,M) -> (P=B*VM, T, C) contiguous paths; fused
// ht = broadcast(b1) init (gemm1 accumulates atomically on top).
// ---------------------------------------------------------------------------
__global__ __launch_bounds__(256) void transpose_kernel(const float* __restrict__ inp,
                                                        float* __restrict__ tp,
                                                        const float* __restrict__ b1,
                                                        float* __restrict__ ht) {
  const int b = blockIdx.x;       // 0..63
  const int tile = blockIdx.y;    // 0..3
  const int t0 = tile * TT;
  const int tid = threadIdx.x;
  __shared__ float lds[3 * TT * VM];  // 7650 floats = 30.6 KB

  const float* src = inp + (size_t)b * 3 * T_PTS * VM;
  for (int idx = tid; idx < 3 * TT * VM; idx += 256) {
    const int c = idx / (TT * VM);
    const int rem = idx - c * (TT * VM);
    lds[idx] = src[(c * T_PTS + t0) * VM + rem];
  }
  __syncthreads();

  for (int idx = tid; idx < VM * TT * 3; idx += 256) {
    const int vm = idx / (TT * 3);
    const int i = idx - vm * (TT * 3);
    const int tt = i / 3;
    const int c = i - tt * 3;
    tp[((size_t)(b * VM + vm) * T_PTS + t0 + tt) * 3 + c] = lds[(c * TT + tt) * VM + vm];
  }

  if (tile == 0) {
    // ht[j][bb] = b1[j] for j in [8b, 8b+8)
    for (int idx = tid; idx < 8 * 64; idx += 256)
      ht[(size_t)(8 * b) * 64 + idx] = b1[8 * b + (idx >> 6)];
  }
}

// ---------------------------------------------------------------------------
// Kernel 1: signatures. One PATH per WAVE, one wave per block (2176 blocks,
// 8-9 waves/CU everywhere). 64 lanes x 5 segments each, then the Chen
// combine: 4 DPP row-local Kogge-Stone rounds (off 1,2,4,8; VALU pipe,
// zero-fill = identity) + 2 maskless __shfl_xor butterfly rounds (off 16,32).
// DS-pipe traffic drops 720 -> 240 ops/wave vs the all-shfl version, and
// the row rounds have ~zero cross-lane latency. Output TRANSPOSED:
// St[k][b], k = vm*120 + c.
// ---------------------------------------------------------------------------
__global__ __launch_bounds__(64)
__attribute__((amdgpu_waves_per_eu(1)))
void sig_kernel(const float* __restrict__ tp, float* __restrict__ St) {
  const int lane = threadIdx.x & 63;
  const int p = blockIdx.x;         // 2176 paths
  const int t0 = lane * CHUNK;

  const float* bp = tp + (size_t)p * (T_PTS * 3) + t0 * 3;

  float a1[3], a2[9], a3[27], a4[81];
#pragma unroll
  for (int i = 0; i < 3; i++) a1[i] = 0.f;
#pragma unroll
  for (int i = 0; i < 9; i++) a2[i] = 0.f;
#pragma unroll
  for (int i = 0; i < 27; i++) a3[i] = 0.f;
#pragma unroll
  for (int i = 0; i < 81; i++) a4[i] = 0.f;

  float x0 = bp[0], x1 = bp[1], x2 = bp[2];
#pragma unroll
  for (int s = 0; s < CHUNK; s++) {
    // Over-reads (up to point 320) stay inside ws (St follows tp) and are
    // masked off below.
    const float y0 = bp[3 * s + 3];
    const float y1 = bp[3 * s + 4];
    const float y2 = bp[3 * s + 5];
    const bool valid = (t0 + s) < N_SEG;
    const float d0 = valid ? (y0 - x0) : 0.0f;
    const float d1 = valid ? (y1 - x1) : 0.0f;
    const float d2 = valid ? (y2 - x2) : 0.0f;
    sig_append(a1, a2, a3, a4, d0, d1, d2);
    x0 = y0; x1 = y1; x2 = y2;
  }

  // Row-local suffix Chen product (16-lane Kogge-Stone via DPP).
  chen_round<1>(a1, a2, a3, a4);
  chen_round<2>(a1, a2, a3, a4);
  chen_round<4>(a1, a2, a3, a4);
  chen_round<8>(a1, a2, a3, a4);
  // Cross-row butterfly: lane 0 <- S(0..31) <- S(0..63).
  chen_round<16>(a1, a2, a3, a4);
  chen_round<32>(a1, a2, a3, a4);

  if (lane == 0) {
    const int b = p / VM;
    const int vm = p - b * VM;
    float* dst = St + (size_t)(vm * SIGC) * 64 + b;  // St[(vm*120+i)*64 + b]
#pragma unroll
    for (int i = 0; i < 3; i++) dst[(size_t)i * 64] = a1[i];
#pragma unroll
    for (int i = 0; i < 9; i++) dst[(size_t)(3 + i) * 64] = a2[i];
#pragma unroll
    for (int i = 0; i < 27; i++) dst[(size_t)(12 + i) * 64] = a3[i];
#pragma unroll
    for (int i = 0; i < 81; i++) dst[(size_t)(39 + i) * 64] = a4[i];
  }
}

// ---------------------------------------------------------------------------
// Kernel 2: ht[j][b] += sum_k St[k][b] * W1[j][k].  lane = b (M=64=wave).
// 6144 waves: 48 K-splits (85 k each) x 128 j-groups (4 j each) -> ~4
// waves/SIMD for latency hiding. St chunk fully unrolled into 85 VGPRs
// (static indices, no scratch); W1 rows are wave-uniform streams (scalar
// loads, one SGPR operand per FMA). Coalesced atomicAdd epilogue onto the
// b1-initialized ht (48 adds/element, order-independent).
// ---------------------------------------------------------------------------
__global__ __launch_bounds__(256) void gemm1_kernel(const float* __restrict__ St,
                                                    const float* __restrict__ W1,
                                                    float* __restrict__ ht) {
  const int lane = threadIdx.x & 63;
  int wave_id = (blockIdx.x * 256 + threadIdx.x) >> 6;        // 0..6143
  wave_id = __builtin_amdgcn_readfirstlane(wave_id);          // force SGPR
  const int ks = wave_id / 128;   // 0..47  (k-range of 85)
  const int jg = wave_id & 127;   // 0..127 (4 j's each)
  const int k0 = ks * KW;

  const float* stp = St + (size_t)k0 * 64 + lane;
  const float* w0 = W1 + (size_t)(jg * 4 + 0) * FAN1 + k0;    // uniform -> s_load
  const float* w1 = W1 + (size_t)(jg * 4 + 1) * FAN1 + k0;
  const float* w2 = W1 + (size_t)(jg * 4 + 2) * FAN1 + k0;
  const float* w3 = W1 + (size_t)(jg * 4 + 3) * FAN1 + k0;

  float sv[KW];
#pragma unroll
  for (int i = 0; i < KW; i++) sv[i] = stp[(size_t)i * 64];

  float acc0 = 0.f, acc1 = 0.f, acc2 = 0.f, acc3 = 0.f;
#pragma unroll
  for (int i = 0; i < KW; i++) {
    acc0 = fmaf(sv[i], w0[i], acc0);
    acc1 = fmaf(sv[i], w1[i], acc1);
    acc2 = fmaf(sv[i], w2[i], acc2);
    acc3 = fmaf(sv[i], w3[i], acc3);
  }

  float* hp = ht + (size_t)(jg * 4) * 64 + lane;
  atomicAdd(hp + 0 * 64, acc0);
  atomicAdd(hp + 1 * 64, acc1);
  atomicAdd(hp + 2 * 64, acc2);
  atomicAdd(hp + 3 * 64, acc3);
}

// ---------------------------------------------------------------------------
// Kernel 3: out[b][j] = sum_k2 ht[k2][b] * W2[j][k2] + b2[j].  lane = b.
// Block = one j; 4 waves split k2 (128 each); LDS partial reduce; single
// non-atomic store (no out-init needed).
// ---------------------------------------------------------------------------
__global__ __launch_bounds__(256) void gemm2_kernel(const float* __restrict__ ht,
                                                    const float* __restrict__ W2,
                                                    const float* __restrict__ b2,
                                                    float* __restrict__ out) {
  const int j = blockIdx.x;              // 0..154
  const int lane = threadIdx.x & 63;
  int w = threadIdx.x >> 6;              // 0..3
  w = __builtin_amdgcn_readfirstlane(w);
  __shared__ float red[4][64];

  const float* htp = ht + (size_t)(w * 128) * 64 + lane;
  const float* w2r = W2 + (size_t)j * H1 + w * 128;  // uniform -> s_load
  float acc = 0.f;
#pragma unroll 8
  for (int k = 0; k < 128; k++) acc = fmaf(w2r[k], htp[(size_t)k * 64], acc);

  red[w][lane] = acc;
  __syncthreads();
  if (threadIdx.x < 64) {
    const float tot = red[0][lane] + red[1][lane] + red[2][lane] + red[3][lane];
    out[(size_t)lane * NOUT + j] = tot + b2[j];
  }
}

// ---------------------------------------------------------------------------
extern "C" void kernel_launch(void* const* d_in, const int* in_sizes, int n_in,
                              void* d_out, int out_size, void* d_ws, size_t ws_size,
                              hipStream_t stream) {
  const float* inp = (const float*)d_in[0];  // (64,3,300,17,2)
  const float* W1  = (const float*)d_in[1];  // (512,4080)
  const float* b1  = (const float*)d_in[2];  // (512,)
  const float* W2  = (const float*)d_in[3];  // (155,512)
  const float* b2  = (const float*)d_in[4];  // (155,)
  float* out = (float*)d_out;                // (64,155)

  // ws layout (floats): tp | St | ht   (~9.0 MB total)
  float* tpbuf = (float*)d_ws;                       // 2176*900
  float* St    = tpbuf + (size_t)NPATH * T_PTS * 3;  // 4080*64
  float* ht    = St + (size_t)FAN1 * 64;             // 512*64

  transpose_kernel<<<dim3(B_SZ, 4), 256, 0, stream>>>(inp, tpbuf, b1, ht);
  sig_kernel<<<NPATH, 64, 0, stream>>>(tpbuf, St);
  gemm1_kernel<<<KSPL * 128 / 4, 256, 0, stream>>>(St, W1, ht);
  gemm2_kernel<<<NOUT, 256, 0, stream>>>(ht, W2, b2, out);
}

// Round 3
// 113.956 us; speedup vs baseline: 1.1556x; 1.0442x over previous
//
#include <hip/hip_runtime.h>
#include <hip/hip_bf16.h>

// Problem shapes
#define B_SZ 64
#define T_PTS 300
#define N_SEG 299
#define VM 34            // 17*2
#define NPATH (B_SZ*VM)  // 2176
#define SIGC 120         // 3+9+27+81
#define FAN1 4080        // 34*120
#define H1 512
#define NOUT 155
#define CHUNK 5          // segments per lane (64*5=320 >= 299)
#define TT 75            // transpose t-tile (300/4)
#define KSPL 48          // gemm1 K-splits
#define KW 85            // k per wave (48*85 = 4080)

// ---------------------------------------------------------------------------
// Absorb one linear segment with increment d into state a1..a4.
// Horner-factored: a segment signature is exp(d), so every level is a tensor
// power of d and the update nests in the trailing index:
//   n4[ijkl] = a4 + d[l]*X[ijk], X = a3 + d[k]*Y[ij], Y = a2/2 + d[j]*Z[i],
//   Z = a1/6 + d[i]/24          (expansion == a3(x)d + a2(x)d^2/2! + ...)
// 189 VALU ops vs ~480 for the explicit-tensor-power form. All indices
// compile-time constant -> stays in VGPRs.
// ---------------------------------------------------------------------------
__device__ __forceinline__ void sig_append(float a1[3], float a2[9], float a3[27], float a4[81],
                                           float d0, float d1, float d2) {
  const float d[3] = {d0, d1, d2};

  // Level 4 (uses OLD a1,a2,a3)
  float Z[3], Y[9], X[27];
#pragma unroll
  for (int i = 0; i < 3; i++) Z[i] = fmaf(d[i], 1.0f / 24.0f, (1.0f / 6.0f) * a1[i]);
#pragma unroll
  for (int e = 0; e < 9; e++) Y[e] = fmaf(d[e % 3], Z[e / 3], 0.5f * a2[e]);
#pragma unroll
  for (int e = 0; e < 27; e++) X[e] = fmaf(d[e % 3], Y[e / 3], a3[e]);
#pragma unroll
  for (int e = 0; e < 81; e++) a4[e] = fmaf(d[e % 3], X[e / 3], a4[e]);

  // Level 3 (uses OLD a1,a2)
  float Z3[3], Y3[9];
#pragma unroll
  for (int i = 0; i < 3; i++) Z3[i] = fmaf(d[i], 1.0f / 6.0f, 0.5f * a1[i]);
#pragma unroll
  for (int e = 0; e < 9; e++) Y3[e] = fmaf(d[e % 3], Z3[e / 3], a2[e]);
#pragma unroll
  for (int e = 0; e < 27; e++) a3[e] = fmaf(d[e % 3], Y3[e / 3], a3[e]);

  // Level 2 (uses OLD a1)
  float Z2[3];
#pragma unroll
  for (int i = 0; i < 3; i++) Z2[i] = fmaf(d[i], 0.5f, a1[i]);
#pragma unroll
  for (int e = 0; e < 9; e++) a2[e] = fmaf(d[e % 3], Z2[e / 3], a2[e]);

#pragma unroll
  for (int i = 0; i < 3; i++) a1[i] += d[i];
}

// ---------------------------------------------------------------------------
// Cross-lane fetch for the Chen combine.
//   OFF < 16 : DPP row_shl:OFF  -> lane i reads lane i+OFF within its 16-lane
//              row; out-of-row lanes get 0 (= Chen identity). VALU pipe, no
//              DS traffic, no mask-multiply needed.
//   OFF >= 16: __shfl_xor butterfly. Only lane 0's chain is consumed; its
//              partners (lane 16 pre-round, lane 32 post-round-16) are always
//              valid suffix products, so no mask is needed.
// ---------------------------------------------------------------------------
template <int OFF>
__device__ __forceinline__ float lane_down(float x) {
  if constexpr (OFF < 16) {
    return __int_as_float(__builtin_amdgcn_update_dpp(
        0, __float_as_int(x), 0x100 + OFF /*row_shl:OFF*/, 0xF, 0xF, true));
  } else {
    return __shfl_xor(x, OFF);
  }
}

// One Chen-combine round: state <- state (x) fetched-state.
// (No Horner here: the fetched B-levels are a general group element, not
//  tensor powers of one vector, so the 4-term form is minimal.)
template <int OFF>
__device__ __forceinline__ void chen_round(float a1[3], float a2[9], float a3[27], float a4[81]) {
  float B1[3], B2[9], B3[27];
#pragma unroll
  for (int i = 0; i < 3; i++) B1[i] = lane_down<OFF>(a1[i]);
#pragma unroll
  for (int i = 0; i < 9; i++) B2[i] = lane_down<OFF>(a2[i]);
#pragma unroll
  for (int i = 0; i < 27; i++) B3[i] = lane_down<OFF>(a3[i]);

#pragma unroll
  for (int e = 0; e < 81; e++) {
    const float b4 = lane_down<OFF>(a4[e]);  // reads pre-update a4[e]
    float v = a4[e] + b4;
    v = fmaf(a3[e / 3], B1[e % 3], v);
    v = fmaf(a2[e / 9], B2[e % 9], v);
    v = fmaf(a1[e / 27], B3[e % 27], v);
    a4[e] = v;
  }
#pragma unroll
  for (int e = 0; e < 27; e++) {
    float v = a3[e] + B3[e];
    v = fmaf(a2[e / 3], B1[e % 3], v);
    v = fmaf(a1[e / 9], B2[e % 9], v);
    a3[e] = v;
  }
#pragma unroll
  for (int e = 0; e < 9; e++) a2[e] = fmaf(a1[e / 3], B1[e % 3], a2[e] + B2[e]);
#pragma unroll
  for (int i = 0; i < 3; i++) a1[i] += B1[i];
}

// ---------------------------------------------------------------------------
// Kernel 0: transpose (B,C,T,V,M) -> (P=B*VM, T, C) contiguous paths; fused
// ht = broadcast(b1) init (gemm1 accumulates atomically on top).
// ---------------------------------------------------------------------------
__global__ __launch_bounds__(256) void transpose_kernel(const float* __restrict__ inp,
                                                        float* __restrict__ tp,
                                                        const float* __restrict__ b1,
                                                        float* __restrict__ ht) {
  const int b = blockIdx.x;       // 0..63
  const int tile = blockIdx.y;    // 0..3
  const int t0 = tile * TT;
  const int tid = threadIdx.x;
  __shared__ float lds[3 * TT * VM];  // 7650 floats = 30.6 KB

  const float* src = inp + (size_t)b * 3 * T_PTS * VM;
  for (int idx = tid; idx < 3 * TT * VM; idx += 256) {
    const int c = idx / (TT * VM);
    const int rem = idx - c * (TT * VM);
    lds[idx] = src[(c * T_PTS + t0) * VM + rem];
  }
  __syncthreads();

  for (int idx = tid; idx < VM * TT * 3; idx += 256) {
    const int vm = idx / (TT * 3);
    const int i = idx - vm * (TT * 3);
    const int tt = i / 3;
    const int c = i - tt * 3;
    tp[((size_t)(b * VM + vm) * T_PTS + t0 + tt) * 3 + c] = lds[(c * TT + tt) * VM + vm];
  }

  if (tile == 0) {
    // ht[j][bb] = b1[j] for j in [8b, 8b+8)
    for (int idx = tid; idx < 8 * 64; idx += 256)
      ht[(size_t)(8 * b) * 64 + idx] = b1[8 * b + (idx >> 6)];
  }
}

// ---------------------------------------------------------------------------
// Kernel 1: signatures. One PATH per WAVE, one wave per block (2176 blocks,
// 8-9 waves/CU everywhere). 64 lanes x 5 Horner-appends each, then the Chen
// combine: 4 DPP row-local Kogge-Stone rounds (off 1,2,4,8; VALU pipe,
// zero-fill = identity) + 2 maskless __shfl_xor butterfly rounds (off 16,32).
// Output TRANSPOSED: St[k][b], k = vm*120 + c.
// ---------------------------------------------------------------------------
__global__ __launch_bounds__(64)
__attribute__((amdgpu_waves_per_eu(1)))
void sig_kernel(const float* __restrict__ tp, float* __restrict__ St) {
  const int lane = threadIdx.x & 63;
  const int p = blockIdx.x;         // 2176 paths
  const int t0 = lane * CHUNK;

  const float* bp = tp + (size_t)p * (T_PTS * 3) + t0 * 3;

  float a1[3], a2[9], a3[27], a4[81];
#pragma unroll
  for (int i = 0; i < 3; i++) a1[i] = 0.f;
#pragma unroll
  for (int i = 0; i < 9; i++) a2[i] = 0.f;
#pragma unroll
  for (int i = 0; i < 27; i++) a3[i] = 0.f;
#pragma unroll
  for (int i = 0; i < 81; i++) a4[i] = 0.f;

  float x0 = bp[0], x1 = bp[1], x2 = bp[2];
#pragma unroll
  for (int s = 0; s < CHUNK; s++) {
    // Over-reads (up to point 320) stay inside ws (St follows tp) and are
    // masked off below.
    const float y0 = bp[3 * s + 3];
    const float y1 = bp[3 * s + 4];
    const float y2 = bp[3 * s + 5];
    const bool valid = (t0 + s) < N_SEG;
    const float d0 = valid ? (y0 - x0) : 0.0f;
    const float d1 = valid ? (y1 - x1) : 0.0f;
    const float d2 = valid ? (y2 - x2) : 0.0f;
    sig_append(a1, a2, a3, a4, d0, d1, d2);
    x0 = y0; x1 = y1; x2 = y2;
  }

  // Row-local suffix Chen product (16-lane Kogge-Stone via DPP).
  chen_round<1>(a1, a2, a3, a4);
  chen_round<2>(a1, a2, a3, a4);
  chen_round<4>(a1, a2, a3, a4);
  chen_round<8>(a1, a2, a3, a4);
  // Cross-row butterfly: lane 0 <- S(0..31) <- S(0..63).
  chen_round<16>(a1, a2, a3, a4);
  chen_round<32>(a1, a2, a3, a4);

  if (lane == 0) {
    const int b = p / VM;
    const int vm = p - b * VM;
    float* dst = St + (size_t)(vm * SIGC) * 64 + b;  // St[(vm*120+i)*64 + b]
#pragma unroll
    for (int i = 0; i < 3; i++) dst[(size_t)i * 64] = a1[i];
#pragma unroll
    for (int i = 0; i < 9; i++) dst[(size_t)(3 + i) * 64] = a2[i];
#pragma unroll
    for (int i = 0; i < 27; i++) dst[(size_t)(12 + i) * 64] = a3[i];
#pragma unroll
    for (int i = 0; i < 81; i++) dst[(size_t)(39 + i) * 64] = a4[i];
  }
}

// ---------------------------------------------------------------------------
// Kernel 2: ht[j][b] += sum_k St[k][b] * W1[j][k].  lane = b (M=64=wave).
// 6144 waves: 48 K-splits (85 k each) x 128 j-groups (4 j each) -> ~4
// waves/SIMD for latency hiding. St chunk fully unrolled into 85 VGPRs
// (static indices, no scratch); W1 rows are wave-uniform streams (scalar
// loads, one SGPR operand per FMA). Coalesced atomicAdd epilogue onto the
// b1-initialized ht (48 adds/element, order-independent).
// ---------------------------------------------------------------------------
__global__ __launch_bounds__(256) void gemm1_kernel(const float* __restrict__ St,
                                                    const float* __restrict__ W1,
                                                    float* __restrict__ ht) {
  const int lane = threadIdx.x & 63;
  int wave_id = (blockIdx.x * 256 + threadIdx.x) >> 6;        // 0..6143
  wave_id = __builtin_amdgcn_readfirstlane(wave_id);          // force SGPR
  const int ks = wave_id / 128;   // 0..47  (k-range of 85)
  const int jg = wave_id & 127;   // 0..127 (4 j's each)
  const int k0 = ks * KW;

  const float* stp = St + (size_t)k0 * 64 + lane;
  const float* w0 = W1 + (size_t)(jg * 4 + 0) * FAN1 + k0;    // uniform -> s_load
  const float* w1 = W1 + (size_t)(jg * 4 + 1) * FAN1 + k0;
  const float* w2 = W1 + (size_t)(jg * 4 + 2) * FAN1 + k0;
  const float* w3 = W1 + (size_t)(jg * 4 + 3) * FAN1 + k0;

  float sv[KW];
#pragma unroll
  for (int i = 0; i < KW; i++) sv[i] = stp[(size_t)i * 64];

  float acc0 = 0.f, acc1 = 0.f, acc2 = 0.f, acc3 = 0.f;
#pragma unroll
  for (int i = 0; i < KW; i++) {
    acc0 = fmaf(sv[i], w0[i], acc0);
    acc1 = fmaf(sv[i], w1[i], acc1);
    acc2 = fmaf(sv[i], w2[i], acc2);
    acc3 = fmaf(sv[i], w3[i], acc3);
  }

  float* hp = ht + (size_t)(jg * 4) * 64 + lane;
  atomicAdd(hp + 0 * 64, acc0);
  atomicAdd(hp + 1 * 64, acc1);
  atomicAdd(hp + 2 * 64, acc2);
  atomicAdd(hp + 3 * 64, acc3);
}

// ---------------------------------------------------------------------------
// Kernel 3: out[b][j] = sum_k2 ht[k2][b] * W2[j][k2] + b2[j].  lane = b.
// Block = one j; 4 waves split k2 (128 each); LDS partial reduce; single
// non-atomic store (no out-init needed).
// ---------------------------------------------------------------------------
__global__ __launch_bounds__(256) void gemm2_kernel(const float* __restrict__ ht,
                                                    const float* __restrict__ W2,
                                                    const float* __restrict__ b2,
                                                    float* __restrict__ out) {
  const int j = blockIdx.x;              // 0..154
  const int lane = threadIdx.x & 63;
  int w = threadIdx.x >> 6;              // 0..3
  w = __builtin_amdgcn_readfirstlane(w);
  __shared__ float red[4][64];

  const float* htp = ht + (size_t)(w * 128) * 64 + lane;
  const float* w2r = W2 + (size_t)j * H1 + w * 128;  // uniform -> s_load
  float acc = 0.f;
#pragma unroll 8
  for (int k = 0; k < 128; k++) acc = fmaf(w2r[k], htp[(size_t)k * 64], acc);

  red[w][lane] = acc;
  __syncthreads();
  if (threadIdx.x < 64) {
    const float tot = red[0][lane] + red[1][lane] + red[2][lane] + red[3][lane];
    out[(size_t)lane * NOUT + j] = tot + b2[j];
  }
}

// ---------------------------------------------------------------------------
extern "C" void kernel_launch(void* const* d_in, const int* in_sizes, int n_in,
                              void* d_out, int out_size, void* d_ws, size_t ws_size,
                              hipStream_t stream) {
  const float* inp = (const float*)d_in[0];  // (64,3,300,17,2)
  const float* W1  = (const float*)d_in[1];  // (512,4080)
  const float* b1  = (const float*)d_in[2];  // (512,)
  const float* W2  = (const float*)d_in[3];  // (155,512)
  const float* b2  = (const float*)d_in[4];  // (155,)
  float* out = (float*)d_out;                // (64,155)

  // ws layout (floats): tp | St | ht   (~9.0 MB total)
  float* tpbuf = (float*)d_ws;                       // 2176*900
  float* St    = tpbuf + (size_t)NPATH * T_PTS * 3;  // 4080*64
  float* ht    = St + (size_t)FAN1 * 64;             // 512*64

  transpose_kernel<<<dim3(B_SZ, 4), 256, 0, stream>>>(inp, tpbuf, b1, ht);
  sig_kernel<<<NPATH, 64, 0, stream>>>(tpbuf, St);
  gemm1_kernel<<<KSPL * 128 / 4, 256, 0, stream>>>(St, W1, ht);
  gemm2_kernel<<<NOUT, 256, 0, stream>>>(ht, W2, b2, out);
}